// Round 1
// baseline (255.490 us; speedup 1.0000x reference)
//
#include <hip/hip_runtime.h>
#include <math.h>

#define N1 1024
#define DPROJ 1024
#define M_NODES 4368
#define N2 (N1 + M_NODES)      // 5392
#define L_LEAVES 4096
#define INV_T (1.0f / 0.07f)

// ---------------------------------------------------------------------------
// Kernel A: inverse norms of all 5392 k-rows (rows 0..1023 are q rows).
// invk[j] = 1 / max(||row_j||, 1e-12)
// ---------------------------------------------------------------------------
__global__ __launch_bounds__(256) void norms_kernel(
    const float* __restrict__ q, const float* __restrict__ vc,
    float* __restrict__ invk) {
  int row = blockIdx.x;
  const float* src = (row < N1) ? q + (size_t)row * DPROJ
                                : vc + (size_t)(row - N1) * DPROJ;
  float s = 0.f;
  for (int c = threadIdx.x; c < DPROJ; c += 256) {
    float v = src[c];
    s += v * v;
  }
  for (int off = 32; off > 0; off >>= 1) s += __shfl_down(s, off);
  __shared__ float wsum[4];
  int lane = threadIdx.x & 63, wid = threadIdx.x >> 6;
  if (lane == 0) wsum[wid] = s;
  __syncthreads();
  if (threadIdx.x == 0) {
    float t = wsum[0] + wsum[1] + wsum[2] + wsum[3];
    invk[row] = 1.0f / fmaxf(sqrtf(t), 1e-12f);
  }
}

// ---------------------------------------------------------------------------
// Kernel B: logits[i][j] = (q_i . k_j) * invk[i] * invk[j] / T
// fp32 tiled GEMM, 64x64 tile, 256 threads, 4x4 per thread, BK=16.
// k_j = q_j for j<1024 else vc_{j-1024}.
// ---------------------------------------------------------------------------
#define BM 64
#define BN 64
#define BK 16

__global__ __launch_bounds__(256) void gemm_kernel(
    const float* __restrict__ q, const float* __restrict__ vc,
    const float* __restrict__ invk, float* __restrict__ logits) {
  __shared__ float As[BK][BM];
  __shared__ float Bs[BK][BN];
  const int bn = blockIdx.x, bm = blockIdx.y;
  const int i0 = bm * BM, j0 = bn * BN;
  const int t = threadIdx.x;
  const int tx = t & 15;   // n direction (0..15)
  const int ty = t >> 4;   // m direction (0..15)
  const int lr = t >> 2;        // tile row 0..63
  const int lc = (t & 3) * 4;   // k-seg start 0,4,8,12

  float acc[4][4] = {};

  const float* arow_base = q + (size_t)(i0 + lr) * DPROJ;
  const int j = j0 + lr;
  const float* brow_base = nullptr;
  if (j < N2)
    brow_base = (j < N1) ? q + (size_t)j * DPROJ
                         : vc + (size_t)(j - N1) * DPROJ;

  for (int k0 = 0; k0 < DPROJ; k0 += BK) {
    float4 av = *(const float4*)(arow_base + k0 + lc);
    As[lc + 0][lr] = av.x;
    As[lc + 1][lr] = av.y;
    As[lc + 2][lr] = av.z;
    As[lc + 3][lr] = av.w;

    float4 bv = make_float4(0.f, 0.f, 0.f, 0.f);
    if (brow_base) bv = *(const float4*)(brow_base + k0 + lc);
    Bs[lc + 0][lr] = bv.x;
    Bs[lc + 1][lr] = bv.y;
    Bs[lc + 2][lr] = bv.z;
    Bs[lc + 3][lr] = bv.w;

    __syncthreads();

#pragma unroll
    for (int kk = 0; kk < BK; ++kk) {
      float4 a = *(const float4*)&As[kk][ty * 4];
      float4 b = *(const float4*)&Bs[kk][tx * 4];
      float am[4] = {a.x, a.y, a.z, a.w};
      float bn_[4] = {b.x, b.y, b.z, b.w};
#pragma unroll
      for (int mi = 0; mi < 4; ++mi)
#pragma unroll
        for (int ni = 0; ni < 4; ++ni) acc[mi][ni] += am[mi] * bn_[ni];
    }
    __syncthreads();
  }

#pragma unroll
  for (int mi = 0; mi < 4; ++mi) {
    int i = i0 + ty * 4 + mi;
    float si = invk[i] * INV_T;
#pragma unroll
    for (int ni = 0; ni < 4; ++ni) {
      int jj = j0 + tx * 4 + ni;
      if (jj < N2) logits[(size_t)i * N2 + jj] = acc[mi][ni] * si * invk[jj];
    }
  }
}

// ---------------------------------------------------------------------------
// Kernel C: per query-row i, compute the 3 per-depth cross-entropies and
// atomically accumulate the loss. Tree masks are computed analytically:
//   leaves: ids 0..4095; depth-2: 4096+c2 (c2 = leaf>>4); depth-1: 4352+c1
//   (c1 = leaf>>8).
//   slot2: pos = {nid==lab};               neg = !pos
//   slot1: pos = S[p2]\{lab};              neg = !inS2
//   slot0: pos = S[p1]\S[p2];              neg = !inS1
// Masked (non-neg) entries contribute exp(0)=1 to the logsumexp.
// Since |logit| <= 1/0.07, a max-free fp32 sum of exps is safe.
// ---------------------------------------------------------------------------
__global__ __launch_bounds__(256) void loss_kernel(
    const float* __restrict__ logits, const int* __restrict__ labels,
    const float* __restrict__ depth, float* __restrict__ out) {
  __shared__ int lab_s[N1];
  const int i = blockIdx.x;
  for (int jj = threadIdx.x; jj < N1; jj += 256) lab_s[jj] = labels[jj];
  __syncthreads();
  const int lab = lab_s[i];
  const int a2 = lab >> 4, a1 = lab >> 8;
  const float* row = logits + (size_t)i * N2;

  float psum0 = 0, psum1 = 0, psum2 = 0;
  float nsum0 = 0, nsum1 = 0, nsum2 = 0;
  int pcnt0 = 0, pcnt1 = 0, pcnt2 = 0;
  int ncnt0 = 0, ncnt1 = 0, ncnt2 = 0;

  for (int jj = threadIdx.x; jj < N2; jj += 256) {
    float l = row[jj];
    int nid = (jj < N1) ? lab_s[jj] : (jj - N1);
    bool isLeaf = nid < L_LEAVES;
    bool isD2 = (nid >= L_LEAVES) && (nid < L_LEAVES + 256);
    bool eqLeaf = (nid == lab);
    bool inS2 = (nid == L_LEAVES + a2) || (isLeaf && ((nid >> 4) == a2));
    bool inS1 = (nid == L_LEAVES + 256 + a1) ||
                (isD2 && (((nid - L_LEAVES) >> 4) == a1)) ||
                (isLeaf && ((nid >> 8) == a1));
    float e = __expf(l);
    if (eqLeaf) { psum2 += l; pcnt2++; } else { nsum2 += e; ncnt2++; }
    if (inS2) { if (!eqLeaf) { psum1 += l; pcnt1++; } } else { nsum1 += e; ncnt1++; }
    if (inS1) { if (!inS2) { psum0 += l; pcnt0++; } } else { nsum0 += e; ncnt0++; }
  }

  float vals[12] = {psum0, psum1, psum2, nsum0, nsum1, nsum2,
                    (float)pcnt0, (float)pcnt1, (float)pcnt2,
                    (float)ncnt0, (float)ncnt1, (float)ncnt2};
  __shared__ float red[4][12];
  const int lane = threadIdx.x & 63, wid = threadIdx.x >> 6;
#pragma unroll
  for (int v = 0; v < 12; ++v) {
    float x = vals[v];
    for (int off = 32; off > 0; off >>= 1) x += __shfl_down(x, off);
    if (lane == 0) red[wid][v] = x;
  }
  __syncthreads();
  if (threadIdx.x == 0) {
    float tot[12];
#pragma unroll
    for (int v = 0; v < 12; ++v)
      tot[v] = red[0][v] + red[1][v] + red[2][v] + red[3][v];
    float ce_sum = 0.f;
#pragma unroll
    for (int s = 0; s < 3; ++s) {
      float psum = tot[s], nsum = tot[3 + s];
      float pcnt = tot[6 + s], ncnt = tot[9 + s];
      float pl = psum / fmaxf(pcnt, 1e-6f);
      float zcnt = (float)N2 - ncnt;  // masked entries contribute exp(0)=1
      float total = nsum + zcnt + __expf(pl);
      ce_sum += logf(total) - pl;
    }
    float d = depth[lab];
    float contrib = ce_sum / d * (3.0f / (float)N1);
    atomicAdd(&out[0], contrib);
    atomicAdd(&out[1], contrib);
  }
}

// ---------------------------------------------------------------------------
extern "C" void kernel_launch(void* const* d_in, const int* in_sizes, int n_in,
                              void* d_out, int out_size, void* d_ws,
                              size_t ws_size, hipStream_t stream) {
  const float* q = (const float*)d_in[0];
  const float* vc = (const float*)d_in[1];
  const int* labels = (const int*)d_in[2];
  const float* depth = (const float*)d_in[6];
  float* out = (float*)d_out;

  float* invk = (float*)d_ws;           // N2 floats
  float* logits = invk + N2;            // N1*N2 floats (~22 MB)

  hipMemsetAsync(d_out, 0, 2 * sizeof(float), stream);

  norms_kernel<<<N2, 256, 0, stream>>>(q, vc, invk);

  dim3 grid((N2 + BN - 1) / BN, N1 / BM);
  gemm_kernel<<<grid, 256, 0, stream>>>(q, vc, invk, logits);

  loss_kernel<<<N1, 256, 0, stream>>>(logits, labels, depth, out);
}

// Round 2
// 80.606 us; speedup vs baseline: 3.1696x; 3.1696x over previous
//
#include <hip/hip_runtime.h>
#include <math.h>

#define N1 1024
#define DPROJ 1024
#define M_NODES 4368
#define N2 (N1 + M_NODES)      // 5392
#define N2P 5504               // padded to 43*128 for the GEMM
#define L_LEAVES 4096
#define INV_T (1.0f / 0.07f)

typedef __bf16 bf16;
typedef __bf16 bf16x4 __attribute__((ext_vector_type(4)));
typedef __bf16 bf16x8 __attribute__((ext_vector_type(8)));
typedef float f32x4 __attribute__((ext_vector_type(4)));

// ---------------------------------------------------------------------------
// Kernel A: fused normalize + bf16 cast.
// kn[row] = row / max(||row||,1e-12) as bf16; rows >= N2 zero-filled (padding).
// One block per row, 256 threads, 4 elems/thread.
// ---------------------------------------------------------------------------
__global__ __launch_bounds__(256) void normalize_kernel(
    const float* __restrict__ q, const float* __restrict__ vc,
    bf16* __restrict__ kn) {
  const int row = blockIdx.x;
  bf16x4* dst = (bf16x4*)(kn + (size_t)row * DPROJ);
  if (row >= N2) {
    bf16x4 z = {(bf16)0.f, (bf16)0.f, (bf16)0.f, (bf16)0.f};
    dst[threadIdx.x] = z;
    return;
  }
  const float* src = (row < N1) ? q + (size_t)row * DPROJ
                                : vc + (size_t)(row - N1) * DPROJ;
  float4 v = ((const float4*)src)[threadIdx.x];
  float s = v.x * v.x + v.y * v.y + v.z * v.z + v.w * v.w;
  for (int off = 32; off > 0; off >>= 1) s += __shfl_down(s, off);
  __shared__ float wsum[4];
  const int lane = threadIdx.x & 63, wid = threadIdx.x >> 6;
  if (lane == 0) wsum[wid] = s;
  __syncthreads();
  const float tot = wsum[0] + wsum[1] + wsum[2] + wsum[3];
  const float inv = 1.0f / fmaxf(sqrtf(tot), 1e-12f);
  bf16x4 o = {(bf16)(v.x * inv), (bf16)(v.y * inv), (bf16)(v.z * inv),
              (bf16)(v.w * inv)};
  dst[threadIdx.x] = o;
}

// ---------------------------------------------------------------------------
// Kernel B: logits = (KN[0:1024] . KN^T) * INV_T   (NT GEMM, bf16 MFMA)
// m97-style: 128x128 tile, BK=32, 4 waves (2x2), each wave 64x64 (4x4 frags
// of 16x16x32), global_load_lds width=16 staging, single-buffered LDS.
// ---------------------------------------------------------------------------
#define BM 128
#define BN 128
#define BK 32

__device__ __forceinline__ void gload16(const bf16* g, bf16* l) {
  __builtin_amdgcn_global_load_lds(
      (const __attribute__((address_space(1))) void*)g,
      (__attribute__((address_space(3))) void*)l, 16, 0, 0);
}

__global__ __launch_bounds__(256) void mfma_gemm_kernel(
    const bf16* __restrict__ kn, float* __restrict__ logits) {
  __shared__ bf16 As[BM][BK];   // 8 KB, row stride 64 B
  __shared__ bf16 Bs[BN][BK];   // 8 KB
  const int j0 = blockIdx.x * BN;
  const int i0 = blockIdx.y * BM;
  const int t = threadIdx.x;
  const int lane = t & 63, w = t >> 6;
  const int wm = w >> 1, wn = w & 1;   // wave grid 2x2, each 64x64

  f32x4 acc[4][4] = {};

  // Staging: wave w stages 16-row chunks {w, w+4} of A and of B.
  // Per-lane: row_in_chunk = lane>>2, k-offset = (lane&3)*8 elements.
  // LDS dest is wave-uniform base + lane*16 (HW rule) — matches row-major
  // [128][32] bf16 layout exactly (row = 64 B = 4 lanes).
  const int rikA = (lane >> 2);
  const int kk = (lane & 3) * 8;
  const bf16* gA0 = kn + (size_t)(i0 + w * 16 + rikA) * DPROJ + kk;
  const bf16* gA1 = gA0 + (size_t)64 * DPROJ;
  const bf16* gB0 = kn + (size_t)(j0 + w * 16 + rikA) * DPROJ + kk;
  const bf16* gB1 = gB0 + (size_t)64 * DPROJ;
  bf16* lA0 = &As[w * 16][0];
  bf16* lA1 = &As[w * 16 + 64][0];
  bf16* lB0 = &Bs[w * 16][0];
  bf16* lB1 = &Bs[w * 16 + 64][0];

  // Fragment read addresses (within LDS)
  const int ar = wm * 64 + (lane & 15);
  const int br = wn * 64 + (lane & 15);
  const int kf = (lane >> 4) * 8;

  for (int k0 = 0; k0 < DPROJ; k0 += BK) {
    gload16(gA0 + k0, lA0);
    gload16(gA1 + k0, lA1);
    gload16(gB0 + k0, lB0);
    gload16(gB1 + k0, lB1);
    asm volatile("s_waitcnt vmcnt(0)" ::: "memory");
    __syncthreads();

    bf16x8 a[4], b[4];
#pragma unroll
    for (int m = 0; m < 4; ++m)
      a[m] = *(const bf16x8*)&As[ar + m * 16][kf];
#pragma unroll
    for (int n = 0; n < 4; ++n)
      b[n] = *(const bf16x8*)&Bs[br + n * 16][kf];
#pragma unroll
    for (int m = 0; m < 4; ++m)
#pragma unroll
      for (int n = 0; n < 4; ++n)
        acc[m][n] = __builtin_amdgcn_mfma_f32_16x16x32_bf16(
            a[m], b[n], acc[m][n], 0, 0, 0);
    __syncthreads();
  }

  // Epilogue: C/D layout col=lane&15, row=(lane>>4)*4+j  [m89-verified]
  const int cr = (lane >> 4) * 4;
  const int cc = lane & 15;
#pragma unroll
  for (int m = 0; m < 4; ++m) {
#pragma unroll
    for (int n = 0; n < 4; ++n) {
      const int gr = i0 + wm * 64 + m * 16 + cr;
      const int gc = j0 + wn * 64 + n * 16 + cc;
      float* dst = logits + (size_t)gr * N2P + gc;
#pragma unroll
      for (int j = 0; j < 4; ++j)
        dst[(size_t)j * N2P] = acc[m][n][j] * INV_T;
    }
  }
}

// ---------------------------------------------------------------------------
// Kernel C: per query-row CE over the 3 depth slots; tree masks analytic.
//   leaves: 0..4095; depth-2 nodes: 4096+(leaf>>4); depth-1: 4352+(leaf>>8).
// Masked (non-neg) entries contribute exp(0)=1 to logsumexp.
// |logit| <= 1/0.07 -> max-free fp32 expsum is safe.
// ---------------------------------------------------------------------------
__global__ __launch_bounds__(256) void loss_kernel(
    const float* __restrict__ logits, const int* __restrict__ labels,
    const float* __restrict__ depth, float* __restrict__ out) {
  __shared__ int lab_s[N1];
  const int i = blockIdx.x;
  for (int jj = threadIdx.x; jj < N1; jj += 256) lab_s[jj] = labels[jj];
  __syncthreads();
  const int lab = lab_s[i];
  const int a2 = lab >> 4, a1 = lab >> 8;
  const float* row = logits + (size_t)i * N2P;

  float psum0 = 0, psum1 = 0, psum2 = 0;
  float nsum0 = 0, nsum1 = 0, nsum2 = 0;
  int pcnt0 = 0, pcnt1 = 0, pcnt2 = 0;
  int ncnt0 = 0, ncnt1 = 0, ncnt2 = 0;

  for (int jj = threadIdx.x; jj < N2; jj += 256) {
    float l = row[jj];
    int nid = (jj < N1) ? lab_s[jj] : (jj - N1);
    bool isLeaf = nid < L_LEAVES;
    bool isD2 = (nid >= L_LEAVES) && (nid < L_LEAVES + 256);
    bool eqLeaf = (nid == lab);
    bool inS2 = (nid == L_LEAVES + a2) || (isLeaf && ((nid >> 4) == a2));
    bool inS1 = (nid == L_LEAVES + 256 + a1) ||
                (isD2 && (((nid - L_LEAVES) >> 4) == a1)) ||
                (isLeaf && ((nid >> 8) == a1));
    float e = __expf(l);
    if (eqLeaf) { psum2 += l; pcnt2++; } else { nsum2 += e; ncnt2++; }
    if (inS2) { if (!eqLeaf) { psum1 += l; pcnt1++; } } else { nsum1 += e; ncnt1++; }
    if (inS1) { if (!inS2) { psum0 += l; pcnt0++; } } else { nsum0 += e; ncnt0++; }
  }

  float vals[12] = {psum0, psum1, psum2, nsum0, nsum1, nsum2,
                    (float)pcnt0, (float)pcnt1, (float)pcnt2,
                    (float)ncnt0, (float)ncnt1, (float)ncnt2};
  __shared__ float red[4][12];
  const int lane = threadIdx.x & 63, wid = threadIdx.x >> 6;
#pragma unroll
  for (int v = 0; v < 12; ++v) {
    float x = vals[v];
    for (int off = 32; off > 0; off >>= 1) x += __shfl_down(x, off);
    if (lane == 0) red[wid][v] = x;
  }
  __syncthreads();
  if (threadIdx.x == 0) {
    float tot[12];
#pragma unroll
    for (int v = 0; v < 12; ++v)
      tot[v] = red[0][v] + red[1][v] + red[2][v] + red[3][v];
    float ce_sum = 0.f;
#pragma unroll
    for (int s = 0; s < 3; ++s) {
      float psum = tot[s], nsum = tot[3 + s];
      float pcnt = tot[6 + s], ncnt = tot[9 + s];
      float pl = psum / fmaxf(pcnt, 1e-6f);
      float zcnt = (float)N2 - ncnt;  // masked entries: exp(0)=1 each
      float total = nsum + zcnt + __expf(pl);
      ce_sum += logf(total) - pl;
    }
    float d = depth[lab];
    float contrib = ce_sum / d * (3.0f / (float)N1);
    atomicAdd(&out[0], contrib);
    atomicAdd(&out[1], contrib);
  }
}

// ---------------------------------------------------------------------------
extern "C" void kernel_launch(void* const* d_in, const int* in_sizes, int n_in,
                              void* d_out, int out_size, void* d_ws,
                              size_t ws_size, hipStream_t stream) {
  const float* q = (const float*)d_in[0];
  const float* vc = (const float*)d_in[1];
  const int* labels = (const int*)d_in[2];
  const float* depth = (const float*)d_in[6];
  float* out = (float*)d_out;

  bf16* kn = (bf16*)d_ws;                               // N2P * DPROJ bf16 (~11.3 MB)
  float* logits = (float*)((char*)d_ws + (size_t)N2P * DPROJ * sizeof(bf16));
                                                        // N1 * N2P f32 (~22.5 MB)

  hipMemsetAsync(d_out, 0, 2 * sizeof(float), stream);

  normalize_kernel<<<N2P, 256, 0, stream>>>(q, vc, kn);

  dim3 grid(N2P / BN, N1 / BM);
  mfma_gemm_kernel<<<grid, 256, 0, stream>>>(kn, logits);

  loss_kernel<<<N1, 256, 0, stream>>>(logits, labels, depth, out);
}